// Round 1
// baseline (67.195 us; speedup 1.0000x reference)
//
#include <hip/hip_runtime.h>
#include <math.h>

// Problem constants (from reference): N=4, E=64, L=512, D=256
#define PN 4
#define PE 64
#define PL 512
#define PD 256

__global__ __launch_bounds__(256) void MeanMaxPooling_84473416778475_kernel(
    const float* __restrict__ doc_state,      // N x L x D
    const float* __restrict__ nodes_mapping,  // N x E x L
    const float* __restrict__ nodes_len,      // N x E
    float* __restrict__ out)                  // N x E x 2D
{
    const int ne  = blockIdx.x;     // 0..N*E-1
    const int n   = ne >> 6;        // / 64
    const int e   = ne & 63;        // % 64
    const int tid = threadIdx.x;    // 0..255
    const int lc  = tid >> 6;       // l-chunk 0..3 (one wave each)
    const int d4  = tid & 63;       // float4 index along D (64 * 4 = 256)

    __shared__ float  smask[PL];         // 2 KB
    __shared__ float4 s_sum[4][64];      // 4 KB
    __shared__ float4 s_max[4][64];      // 4 KB

    // Stage this (n,e)'s token mask: 512 floats, 256 threads -> 2 each.
    {
        const float* mp = nodes_mapping + (size_t)(n * PE + e) * PL;
        smask[tid]       = mp[tid];
        smask[tid + 256] = mp[tid + 256];
    }
    __syncthreads();

    // doc_state for doc n, viewed as float4 [L][64]
    const float4* ds = (const float4*)(doc_state + (size_t)n * PL * PD);

    float4 sum = make_float4(0.f, 0.f, 0.f, 0.f);
    float4 mx  = make_float4(-INFINITY, -INFINITY, -INFINITY, -INFINITY);

    const int l0 = lc * (PL / 4);   // 128 tokens per wave
    #pragma unroll 8
    for (int i = 0; i < PL / 4; ++i) {
        const int l = l0 + i;
        const float  m = smask[l];           // wave-uniform broadcast (free)
        const float4 s = ds[l * 64 + d4];    // coalesced 16B/lane
        // v = mask * state; zeros from unselected tokens DO participate in max
        const float vx = m * s.x, vy = m * s.y, vz = m * s.z, vw = m * s.w;
        sum.x += vx; sum.y += vy; sum.z += vz; sum.w += vw;
        mx.x = fmaxf(mx.x, vx);
        mx.y = fmaxf(mx.y, vy);
        mx.z = fmaxf(mx.z, vz);
        mx.w = fmaxf(mx.w, vw);
    }

    s_sum[lc][d4] = sum;
    s_max[lc][d4] = mx;
    __syncthreads();

    if (lc == 0) {
        #pragma unroll
        for (int j = 1; j < 4; ++j) {
            const float4 s2 = s_sum[j][d4];
            const float4 m2 = s_max[j][d4];
            sum.x += s2.x; sum.y += s2.y; sum.z += s2.z; sum.w += s2.w;
            mx.x = fmaxf(mx.x, m2.x);
            mx.y = fmaxf(mx.y, m2.y);
            mx.z = fmaxf(mx.z, m2.z);
            mx.w = fmaxf(mx.w, m2.w);
        }
        const float len  = nodes_len[n * PE + e];
        const float slen = (len > 0.f) ? len : 1.0f;
        // exact fp32 division to match numpy reference bit-for-bit-ish
        float4 mean;
        mean.x = sum.x / slen;
        mean.y = sum.y / slen;
        mean.z = sum.z / slen;
        mean.w = sum.w / slen;

        float4* o = (float4*)(out + (size_t)(n * PE + e) * 2 * PD);
        o[d4]      = mx;    // max_pooled -> first D
        o[64 + d4] = mean;  // mean_pooled -> second D
    }
}

extern "C" void kernel_launch(void* const* d_in, const int* in_sizes, int n_in,
                              void* d_out, int out_size, void* d_ws, size_t ws_size,
                              hipStream_t stream) {
    const float* doc_state     = (const float*)d_in[0];  // N*L*D
    const float* nodes_mapping = (const float*)d_in[1];  // N*E*L
    const float* nodes_len     = (const float*)d_in[2];  // N*E
    float* out = (float*)d_out;                          // N*E*2D

    dim3 grid(PN * PE);   // 256 blocks
    dim3 block(256);
    MeanMaxPooling_84473416778475_kernel<<<grid, block, 0, stream>>>(
        doc_state, nodes_mapping, nodes_len, out);
}

// Round 2
// 63.492 us; speedup vs baseline: 1.0583x; 1.0583x over previous
//
#include <hip/hip_runtime.h>
#include <math.h>

// Problem constants (from reference): N=4, E=64, L=512, D=256
#define PN 4
#define PE 64
#define PL 512
#define PD 256
#define NWAVES 16          // 1024 threads = 16 waves -> 16 waves/CU (vs 4 before)
#define TOK_PER_WAVE (PL / NWAVES)   // 32 tokens per wave

__global__ __launch_bounds__(64 * NWAVES) void MeanMaxPooling_84473416778475_kernel(
    const float* __restrict__ doc_state,      // N x L x D
    const float* __restrict__ nodes_mapping,  // N x E x L
    const float* __restrict__ nodes_len,      // N x E
    float* __restrict__ out)                  // N x E x 2D
{
    const int ne   = blockIdx.x;     // 0..N*E-1
    const int n    = ne >> 6;        // / 64
    const int e    = ne & 63;        // % 64
    const int tid  = threadIdx.x;    // 0..1023
    const int w    = tid >> 6;       // wave 0..15
    const int lane = tid & 63;       // float4 index along D (64 * 4 = 256)

    __shared__ float  smask[PL];            // 2 KB
    __shared__ float4 s_sum[NWAVES][64];    // 16 KB
    __shared__ float4 s_max[NWAVES][64];    // 16 KB

    // Stage this (n,e)'s token mask: 512 floats.
    if (tid < PL) {
        smask[tid] = nodes_mapping[(size_t)(n * PE + e) * PL + tid];
    }
    __syncthreads();

    // doc_state for doc n, viewed as float4 [L][64]
    const float4* ds = (const float4*)(doc_state + (size_t)n * PL * PD);

    float4 sum = make_float4(0.f, 0.f, 0.f, 0.f);
    float4 mx  = make_float4(-INFINITY, -INFINITY, -INFINITY, -INFINITY);

    const int l0 = w * TOK_PER_WAVE;   // 32 tokens per wave
    #pragma unroll 8
    for (int i = 0; i < TOK_PER_WAVE; ++i) {
        const int l = l0 + i;
        const float  m = smask[l];           // wave-uniform broadcast (free)
        const float4 s = ds[l * 64 + lane];  // coalesced 16B/lane, L2-resident
        // v = mask * state; zeros from unselected tokens DO participate in max
        const float vx = m * s.x, vy = m * s.y, vz = m * s.z, vw = m * s.w;
        sum.x += vx; sum.y += vy; sum.z += vz; sum.w += vw;
        mx.x = fmaxf(mx.x, vx);
        mx.y = fmaxf(mx.y, vy);
        mx.z = fmaxf(mx.z, vz);
        mx.w = fmaxf(mx.w, vw);
    }

    s_sum[w][lane] = sum;
    s_max[w][lane] = mx;
    __syncthreads();

    // Wave 0 reduces the 16 per-wave partials and writes the output.
    if (tid < 64) {
        float4 tsum = s_sum[0][lane];
        float4 tmax = s_max[0][lane];
        #pragma unroll
        for (int j = 1; j < NWAVES; ++j) {
            const float4 s2 = s_sum[j][lane];
            const float4 m2 = s_max[j][lane];
            tsum.x += s2.x; tsum.y += s2.y; tsum.z += s2.z; tsum.w += s2.w;
            tmax.x = fmaxf(tmax.x, m2.x);
            tmax.y = fmaxf(tmax.y, m2.y);
            tmax.z = fmaxf(tmax.z, m2.z);
            tmax.w = fmaxf(tmax.w, m2.w);
        }
        const float len  = nodes_len[n * PE + e];
        const float slen = (len > 0.f) ? len : 1.0f;
        float4 mean;
        mean.x = tsum.x / slen;
        mean.y = tsum.y / slen;
        mean.z = tsum.z / slen;
        mean.w = tsum.w / slen;

        float4* o = (float4*)(out + (size_t)(n * PE + e) * 2 * PD);
        o[lane]      = tmax;   // max_pooled -> first D
        o[64 + lane] = mean;   // mean_pooled -> second D
    }
}

extern "C" void kernel_launch(void* const* d_in, const int* in_sizes, int n_in,
                              void* d_out, int out_size, void* d_ws, size_t ws_size,
                              hipStream_t stream) {
    const float* doc_state     = (const float*)d_in[0];  // N*L*D
    const float* nodes_mapping = (const float*)d_in[1];  // N*E*L
    const float* nodes_len     = (const float*)d_in[2];  // N*E
    float* out = (float*)d_out;                          // N*E*2D

    dim3 grid(PN * PE);        // 256 blocks, ~1 per CU
    dim3 block(64 * NWAVES);   // 1024 threads = 16 waves
    MeanMaxPooling_84473416778475_kernel<<<grid, block, 0, stream>>>(
        doc_state, nodes_mapping, nodes_len, out);
}